// Round 11
// baseline (310.920 us; speedup 1.0000x reference)
//
#include <hip/hip_runtime.h>
#include <stdint.h>

// ---- problem constants ----
#define BATCH 2
#define SEQ   2048
#define NHEAD 16
#define DK    64
#define DMODEL 1024
#define MROWS (BATCH*SEQ)   // 4096

typedef __attribute__((ext_vector_type(8))) __bf16 bf16x8;
typedef __attribute__((ext_vector_type(4))) float f32x4;
typedef __attribute__((ext_vector_type(8))) unsigned short u16x8;
typedef __attribute__((ext_vector_type(4))) unsigned short u16x4;

// 0.125 * log2(e): folded into Q projection so softmax is a bare v_exp_f32 (2^x)
#define QSCALE 0.18033688f

__device__ __forceinline__ unsigned short f2bf(float f) {
  union { float f; uint32_t u; } c; c.f = f;
  uint32_t u = c.u;
  return (unsigned short)((u + 0x7fffu + ((u >> 16) & 1u)) >> 16);
}

// async global->LDS, 16B per lane. LDS dest = wave-uniform base + lane*16.
__device__ __forceinline__ void gld16(const void* g, void* lds) {
  __builtin_amdgcn_global_load_lds(
      (const __attribute__((address_space(1))) void*)g,
      (__attribute__((address_space(3))) void*)lds,
      16, 0, 0);
}

// ---- fp32 -> bf16 convert (7 tensors) + bias-broadcast init of out ----
// blocks [0,6144): X tensors; [6144,8192): W tensors; [8192,10240): out=bias
__global__ __launch_bounds__(256)
void cvt_all(const float* __restrict__ q, const float* __restrict__ k, const float* __restrict__ v,
             const float* __restrict__ Wq, const float* __restrict__ Wk,
             const float* __restrict__ Wv, const float* __restrict__ Wo,
             const float* __restrict__ bo, float* __restrict__ outp,
             unsigned short* __restrict__ Xq, unsigned short* __restrict__ Xk,
             unsigned short* __restrict__ Xv,
             unsigned short* __restrict__ Wqb, unsigned short* __restrict__ Wkb,
             unsigned short* __restrict__ Wvb, unsigned short* __restrict__ Wob) {
  int blk = blockIdx.x;
  if (blk >= 8192) {
    // out = bias (split-K gemm_out atomically accumulates on top)
    int i = (blk - 8192) * 2048 + threadIdx.x * 8;
    float4 b0 = *(const float4*)&bo[i & (DMODEL - 1)];
    float4 b1 = *(const float4*)&bo[(i + 4) & (DMODEL - 1)];
    *(float4*)&outp[i] = b0;
    *(float4*)&outp[i + 4] = b1;
    return;
  }
  const float* in; unsigned short* out; int base;
  if (blk < 6144) {
    int ti = blk >> 11;
    in  = (ti == 0) ? q  : (ti == 1) ? k  : v;
    out = (ti == 0) ? Xq : (ti == 1) ? Xk : Xv;
    base = (blk & 2047) * 2048;
  } else {
    int ti = (blk - 6144) >> 9;
    in  = (ti == 0) ? Wq  : (ti == 1) ? Wk  : (ti == 2) ? Wv  : Wo;
    out = (ti == 0) ? Wqb : (ti == 1) ? Wkb : (ti == 2) ? Wvb : Wob;
    base = ((blk - 6144) & 511) * 2048;
  }
  int i = base + threadIdx.x * 8;
  float4 a = *(const float4*)(in + i);
  float4 b = *(const float4*)(in + i + 4);
  u16x8 o;
  o[0]=f2bf(a.x); o[1]=f2bf(a.y); o[2]=f2bf(a.z); o[3]=f2bf(a.w);
  o[4]=f2bf(b.x); o[5]=f2bf(b.y); o[6]=f2bf(b.z); o[7]=f2bf(b.w);
  *(u16x8*)(out + i) = o;
}

// ---- GEMM: Y[m][n] = sum_{k in [kb,ke)} X[m][k]*W[n][k] (+ bias) ----
// 128x128 tile, BK=64, 256 threads; hoisted LDS offsets + incremental pointers.
// LDS declared in caller (R9 bug: per-instantiation static __shared__ -> 96KB).
// MODE 0/1/3/4: operand-swapped MFMA (reg axis along Y cols -> vector stores).
// MODE 2: V -> permuted VT scatter. MODE 4: f32 atomic accumulate (split-K).
template <int MODE>
__device__ __forceinline__ void gemm_body(unsigned short* __restrict__ lA,
                                          unsigned short* __restrict__ lB,
                                          const unsigned short* __restrict__ X,
                                          const unsigned short* __restrict__ W,
                                          const float* __restrict__ bias,
                                          unsigned short* __restrict__ Yb,
                                          float* __restrict__ Yf,
                                          int rowBase, int colBase, int kb, int ke) {
  const int t = threadIdx.x;
  const int lane = t & 63, wave = t >> 6;
  const int cl = lane & 15, qd = lane >> 4;
  const int wm = wave >> 1, wn = wave & 1;
  const int srow = t >> 3, sslot = t & 7;

  // hoisted LDS read offsets (ushort indices), invariant across the k-loop
  int aoff[2][4], boff[2][4];
  #pragma unroll
  for (int ks = 0; ks < 2; ks++)
    #pragma unroll
    for (int i = 0; i < 4; i++) {
      int ra = wm * 64 + i * 16 + cl;
      aoff[ks][i] = ra * 64 + ((ks * 4 + qd) ^ (ra & 7)) * 8;
      int rb = wn * 64 + i * 16 + cl;
      boff[ks][i] = rb * 64 + ((ks * 4 + qd) ^ (rb & 7)) * 8;
    }
  // incremental staging pointers (advance 64 elems per k-step)
  const unsigned short* xp[4];
  const unsigned short* wp[4];
  #pragma unroll
  for (int i = 0; i < 4; i++) {
    int r = i * 32 + srow;
    int chunk = sslot ^ (r & 7);
    xp[i] = X + (size_t)(rowBase + r) * DMODEL + kb + chunk * 8;
    wp[i] = W + (size_t)(colBase + r) * DMODEL + kb + chunk * 8;
  }

  f32x4 zero = {0.f, 0.f, 0.f, 0.f};
  f32x4 acc[4][4];
  for (int mt = 0; mt < 4; mt++) for (int nt = 0; nt < 4; nt++) acc[mt][nt] = zero;

  for (int k0 = kb; k0 < ke; k0 += 64) {
    __syncthreads();
    #pragma unroll
    for (int i = 0; i < 4; i++) {
      gld16(xp[i], (char*)lA + i * 4096 + wave * 1024);
      gld16(wp[i], (char*)lB + i * 4096 + wave * 1024);
      xp[i] += 64; wp[i] += 64;
    }
    __syncthreads();
    #pragma unroll
    for (int ks = 0; ks < 2; ks++) {
      bf16x8 af[4], bfr[4];
      #pragma unroll
      for (int mt = 0; mt < 4; mt++) af[mt] = *(const bf16x8*)&lA[aoff[ks][mt]];
      #pragma unroll
      for (int nt = 0; nt < 4; nt++) bfr[nt] = *(const bf16x8*)&lB[boff[ks][nt]];
      #pragma unroll
      for (int mt = 0; mt < 4; mt++)
        #pragma unroll
        for (int nt = 0; nt < 4; nt++) {
          if (MODE == 2)
            acc[mt][nt] = __builtin_amdgcn_mfma_f32_16x16x32_bf16(af[mt], bfr[nt], acc[mt][nt], 0, 0, 0);
          else  // swapped: D[m=Ycol][n=Yrow]
            acc[mt][nt] = __builtin_amdgcn_mfma_f32_16x16x32_bf16(bfr[nt], af[mt], acc[mt][nt], 0, 0, 0);
        }
    }
  }

  if (MODE == 2) {
    // original C/D layout: col(Ycol)=cl, row(Yrow)=qd*4+r
    // V projection -> permuted VT[(b*16+h)*64+d][s], s-nibbles reordered per
    // 32-half: l4<4 -> pos 2*l4 ; l4>=4 -> pos 2*(l4-4)+1
    #pragma unroll
    for (int mt = 0; mt < 4; mt++) {
      int row0 = rowBase + wm * 64 + mt * 16 + qd * 4;
      int bb = row0 >> 11;
      int s_in = row0 & 2047;
      int blk = s_in & ~63;
      int n4 = (s_in & 63) >> 2;
      int l4 = n4 & 7;
      int pos = 8 * (n4 >> 3) + ((l4 < 4) ? 2 * l4 : 2 * (l4 - 4) + 1);
      #pragma unroll
      for (int nt = 0; nt < 4; nt++) {
        int c = colBase + wn * 64 + nt * 16 + cl;
        float bv = bias[c];
        int hh = c >> 6, d = c & 63;
        u16x4 v;
        #pragma unroll
        for (int r = 0; r < 4; r++) v[r] = f2bf(acc[mt][nt][r] + bv);
        *(u16x4*)&Yb[(size_t)((bb * NHEAD + hh) * 64 + d) * SEQ + blk + pos * 4] = v;
      }
    }
  } else {
    // swapped C/D layout: n(Yrow)=cl, m(Ycol)=qd*4+r -> vector ops along cols
    #pragma unroll
    for (int nt = 0; nt < 4; nt++) {
      int col = colBase + wn * 64 + nt * 16 + qd * 4;
      f32x4 bv4 = (MODE == 4) ? zero : *(const f32x4*)&bias[col];
      #pragma unroll
      for (int mt = 0; mt < 4; mt++) {
        int row = rowBase + wm * 64 + mt * 16 + cl;
        if (MODE == 4) {
          #pragma unroll
          for (int r = 0; r < 4; r++)
            unsafeAtomicAdd(&Yf[(size_t)row * DMODEL + col + r], acc[mt][nt][r]);
        } else if (MODE == 3) {
          f32x4 v;
          #pragma unroll
          for (int r = 0; r < 4; r++) v[r] = acc[mt][nt][r] + bv4[r];
          *(f32x4*)&Yf[(size_t)row * DMODEL + col] = v;
        } else {
          u16x4 v;
          #pragma unroll
          for (int r = 0; r < 4; r++) {
            float x = acc[mt][nt][r] + bv4[r];
            v[r] = f2bf(MODE == 1 ? x * QSCALE : x);
          }
          *(u16x4*)&Yb[(size_t)row * DMODEL + col] = v;
        }
      }
    }
  }
}

// grid dim3(256,1,3): y-fastest linearization (by = id&31) so the 8 bx-blocks
// sharing an X panel have ids congruent mod 8 => same XCD; per-XCD L2 set ~3MB.
__global__ __launch_bounds__(256)
void gemm_qkv(const unsigned short* __restrict__ Xq, const unsigned short* __restrict__ Xk,
              const unsigned short* __restrict__ Xv,
              const unsigned short* __restrict__ Wq, const unsigned short* __restrict__ Wk,
              const unsigned short* __restrict__ Wv,
              const float* __restrict__ bq, const float* __restrict__ bk,
              const float* __restrict__ bv,
              unsigned short* __restrict__ Q, unsigned short* __restrict__ K,
              unsigned short* __restrict__ VT) {
  __shared__ unsigned short lA[128 * 64];   // 16 KB — shared by all MODE paths
  __shared__ unsigned short lB[128 * 64];   // 16 KB
  int id = blockIdx.x;
  int by = id & 31, bx = id >> 5;
  int z = blockIdx.z;
  if (z == 0)      gemm_body<1>(lA, lB, Xq, Wq, bq, Q,  nullptr, by * 128, bx * 128, 0, DMODEL);
  else if (z == 1) gemm_body<0>(lA, lB, Xk, Wk, bk, K,  nullptr, by * 128, bx * 128, 0, DMODEL);
  else             gemm_body<2>(lA, lB, Xv, Wv, bv, VT, nullptr, by * 128, bx * 128, 0, DMODEL);
}

// grid 512: split-K x2 (id&1 = K-half), atomic f32 accumulate onto bias-inited
// out. Panel-sharers (ids differing by 64) stay congruent mod 8 => same XCD.
__global__ __launch_bounds__(256)
void gemm_out(const unsigned short* __restrict__ CTX, const unsigned short* __restrict__ Wo,
              float* __restrict__ out) {
  __shared__ unsigned short lA[128 * 64];
  __shared__ unsigned short lB[128 * 64];
  int id = blockIdx.x;
  int sp = id & 1;
  int by = (id >> 1) & 31, bx = id >> 6;
  gemm_body<4>(lA, lB, CTX, Wo, nullptr, nullptr, out,
               by * 128, bx * 128, sp * 512, sp * 512 + 512);
}

// ---- flash attention, transposed: S^T = K Q^T, O^T = V^T P^T ----
// R8 body. XCD swizzle: all 16 qt-blocks of one (h,b) land on one XCD so K/V
// tiles are fetched once per XCD (bijective remap of the 512 flat ids).
__global__ __launch_bounds__(256)
void attn(const unsigned short* __restrict__ Q, const unsigned short* __restrict__ K,
          const unsigned short* __restrict__ VT, unsigned short* __restrict__ CTX) {
  __shared__ unsigned short lK[2 * 64 * 64];  // 16 KB (Q staged here first)
  __shared__ unsigned short lV[2 * 64 * 64];  // 16 KB, permuted VT tiles
  const int t = threadIdx.x, lane = t & 63, wave = t >> 6;
  const int cl = lane & 15, qd = lane >> 4;
  // XCD-aware remap: flat -> (xcd = flat&7, loc); (h,b) = p = xcd*4 + loc>>4
  const int flat = blockIdx.x + 16 * blockIdx.y + 256 * blockIdx.z;
  const int loc = flat >> 3;
  const int p = (flat & 7) * 4 + (loc >> 4);
  const int qt = loc & 15, h = p & 15, b = p >> 4;
  const int srow = t >> 3, sslot = t & 7;

  // stage 128 Q rows into lK halves
  #pragma unroll
  for (int half = 0; half < 2; half++)
    #pragma unroll
    for (int i = 0; i < 2; i++) {
      int r = i * 32 + srow;
      int chunk = sslot ^ (r & 7);
      gld16(Q + (size_t)(b * SEQ + qt * 128 + half * 64 + r) * DMODEL + h * 64 + chunk * 8,
            (char*)lK + half * 8192 + i * 4096 + wave * 1024);
    }
  __syncthreads();
  bf16x8 qf[2][2];
  #pragma unroll
  for (int qg = 0; qg < 2; qg++)
    #pragma unroll
    for (int ks = 0; ks < 2; ks++) {
      int r = wave * 16 + cl;
      int slot = (ks * 4 + qd) ^ (r & 7);
      qf[qg][ks] = *(const bf16x8*)&lK[qg * 4096 + r * 64 + slot * 8];
    }
  __syncthreads();  // all waves done reading Q before K staging overwrites

  // hoisted LDS read offsets (kt-invariant)
  int ka[8], va[8];
  #pragma unroll
  for (int ks = 0; ks < 2; ks++)
    #pragma unroll
    for (int nt = 0; nt < 4; nt++) {
      int rk = nt * 16 + cl;
      ka[ks * 4 + nt] = rk * 64 + ((ks * 4 + qd) ^ (rk & 7)) * 8;
    }
  #pragma unroll
  for (int ntp = 0; ntp < 2; ntp++)
    #pragma unroll
    for (int dt = 0; dt < 4; dt++) {
      int d = dt * 16 + cl;
      va[ntp * 4 + dt] = d * 64 + ((4 * ntp + qd) ^ (d & 7)) * 8;
    }

  // stage K/V tile 0 into buffer 0; init incremental prefetch pointers
  const unsigned short* kp[2];
  const unsigned short* vp[2];
  #pragma unroll
  for (int i = 0; i < 2; i++) {
    int r = i * 32 + srow;
    int chunk = sslot ^ (r & 7);
    kp[i] = K + (size_t)(b * SEQ + r) * DMODEL + h * 64 + chunk * 8;
    vp[i] = VT + (size_t)((b * NHEAD + h) * 64 + r) * SEQ + chunk * 8;
    gld16(kp[i], (char*)lK + i * 4096 + wave * 1024);
    gld16(vp[i], (char*)lV + i * 4096 + wave * 1024);
    kp[i] += 64 * DMODEL; vp[i] += 64;
  }

  f32x4 zero = {0.f, 0.f, 0.f, 0.f};
  f32x4 o[2][4];     // o[qg][dt][r] = O^T[d=dt*16+qd*4+r][q=cl]
  f32x4 osum[2];     // row-sum via ones-MFMA
  #pragma unroll
  for (int qg = 0; qg < 2; qg++) {
    #pragma unroll
    for (int dt = 0; dt < 4; dt++) o[qg][dt] = zero;
    osum[qg] = zero;
  }
  bf16x8 ones;
  #pragma unroll
  for (int j = 0; j < 8; j++) ones[j] = (__bf16)1.0f;

  #pragma unroll 2
  for (int kt = 0; kt < SEQ / 64; kt++) {
    const int cb = (kt & 1) * 4096;
    __syncthreads();  // tile kt's loads drained; other buffer free
    if (kt + 1 < SEQ / 64) {
      const int nb = ((kt + 1) & 1) * 8192;
      #pragma unroll
      for (int i = 0; i < 2; i++) {
        gld16(kp[i], (char*)lK + nb + i * 4096 + wave * 1024);
        gld16(vp[i], (char*)lV + nb + i * 4096 + wave * 1024);
        kp[i] += 64 * DMODEL; vp[i] += 64;
      }
    }

    // S^T[kv][q]: A = K rows, B = qf; kf shared across both q-groups
    f32x4 sc[2][4];
    #pragma unroll
    for (int qg = 0; qg < 2; qg++)
      #pragma unroll
      for (int nt = 0; nt < 4; nt++) sc[qg][nt] = zero;
    #pragma unroll
    for (int ks = 0; ks < 2; ks++)
      #pragma unroll
      for (int nt = 0; nt < 4; nt++) {
        bf16x8 kf = *(const bf16x8*)&lK[cb + ka[ks * 4 + nt]];
        sc[0][nt] = __builtin_amdgcn_mfma_f32_16x16x32_bf16(kf, qf[0][ks], sc[0][nt], 0, 0, 0);
        sc[1][nt] = __builtin_amdgcn_mfma_f32_16x16x32_bf16(kf, qf[1][ks], sc[1][nt], 0, 0, 0);
      }

    // P^T = 2^(S^T); pack straight to bf16 frags
    bf16x8 pb[2][2];
    #pragma unroll
    for (int qg = 0; qg < 2; qg++)
      #pragma unroll
      for (int ntp = 0; ntp < 2; ntp++) {
        bf16x8 x;
        #pragma unroll
        for (int j = 0; j < 4; j++)
          x[j] = (__bf16)__builtin_amdgcn_exp2f(sc[qg][2 * ntp][j]);
        #pragma unroll
        for (int j = 0; j < 4; j++)
          x[4 + j] = (__bf16)__builtin_amdgcn_exp2f(sc[qg][2 * ntp + 1][j]);
        pb[qg][ntp] = x;
      }

    // row-sum on the matrix pipe
    #pragma unroll
    for (int qg = 0; qg < 2; qg++) {
      osum[qg] = __builtin_amdgcn_mfma_f32_16x16x32_bf16(ones, pb[qg][0], osum[qg], 0, 0, 0);
      osum[qg] = __builtin_amdgcn_mfma_f32_16x16x32_bf16(ones, pb[qg][1], osum[qg], 0, 0, 0);
    }

    // O^T += V^T P^T; vf shared across both q-groups
    #pragma unroll
    for (int ntp = 0; ntp < 2; ntp++)
      #pragma unroll
      for (int dt = 0; dt < 4; dt++) {
        bf16x8 vf = *(const bf16x8*)&lV[cb + va[ntp * 4 + dt]];
        o[0][dt] = __builtin_amdgcn_mfma_f32_16x16x32_bf16(vf, pb[0][ntp], o[0][dt], 0, 0, 0);
        o[1][dt] = __builtin_amdgcn_mfma_f32_16x16x32_bf16(vf, pb[1][ntp], o[1][dt], 0, 0, 0);
      }
  }

  // epilogue: every lane holds its q-column's sum in osum[qg][0]
  #pragma unroll
  for (int qg = 0; qg < 2; qg++) {
    float inv = 1.f / osum[qg][0];
    int row = b * SEQ + qt * 128 + qg * 64 + wave * 16 + cl;
    #pragma unroll
    for (int dt = 0; dt < 4; dt++) {
      u16x4 v;
      #pragma unroll
      for (int r = 0; r < 4; r++) v[r] = f2bf(o[qg][dt][r] * inv);
      *(u16x4*)&CTX[(size_t)row * DMODEL + h * 64 + dt * 16 + qd * 4] = v;
    }
  }
}

extern "C" void kernel_launch(void* const* d_in, const int* in_sizes, int n_in,
                              void* d_out, int out_size, void* d_ws, size_t ws_size,
                              hipStream_t stream) {
  const float* q  = (const float*)d_in[0];
  const float* k  = (const float*)d_in[1];
  const float* v  = (const float*)d_in[2];
  const float* Wq = (const float*)d_in[3]; const float* bq = (const float*)d_in[4];
  const float* Wk = (const float*)d_in[5]; const float* bk = (const float*)d_in[6];
  const float* Wv = (const float*)d_in[7]; const float* bv = (const float*)d_in[8];
  const float* Wo = (const float*)d_in[9]; const float* bo = (const float*)d_in[10];
  float* out = (float*)d_out;

  char* ws = (char*)d_ws;
  const size_t MB = 1u << 20;
  // Liveness: Wob kept at +70MB (R4-R6 NaN was an Opart->Wob clobber)
  unsigned short* Xq  = (unsigned short*)(ws + 0 * MB);
  unsigned short* Xk  = (unsigned short*)(ws + 8 * MB);
  unsigned short* Xv  = (unsigned short*)(ws + 16 * MB);
  unsigned short* Wqb = (unsigned short*)(ws + 24 * MB);
  unsigned short* Wkb = (unsigned short*)(ws + 26 * MB);
  unsigned short* Wvb = (unsigned short*)(ws + 28 * MB);
  unsigned short* Wob = (unsigned short*)(ws + 70 * MB);
  unsigned short* Qp  = (unsigned short*)(ws + 32 * MB);
  unsigned short* Kp  = (unsigned short*)(ws + 40 * MB);
  unsigned short* VT  = (unsigned short*)(ws + 48 * MB);
  unsigned short* CTX = (unsigned short*)(ws + 56 * MB);

  cvt_all<<<10240, 256, 0, stream>>>(q, k, v, Wq, Wk, Wv, Wo, bo, out,
                                     Xq, Xk, Xv, Wqb, Wkb, Wvb, Wob);

  gemm_qkv<<<dim3(256, 1, 3), 256, 0, stream>>>(
      Xq, Xk, Xv, Wqb, Wkb, Wvb, bq, bk, bv, Qp, Kp, VT);

  attn<<<dim3(SEQ / 128, NHEAD, BATCH), 256, 0, stream>>>(Qp, Kp, VT, CTX);

  gemm_out<<<512, 256, 0, stream>>>(CTX, Wob, out);
}

// Round 12
// 245.709 us; speedup vs baseline: 1.2654x; 1.2654x over previous
//
#include <hip/hip_runtime.h>
#include <stdint.h>

// ---- problem constants ----
#define BATCH 2
#define SEQ   2048
#define NHEAD 16
#define DK    64
#define DMODEL 1024
#define MROWS (BATCH*SEQ)   // 4096

typedef __attribute__((ext_vector_type(8))) __bf16 bf16x8;
typedef __attribute__((ext_vector_type(4))) float f32x4;
typedef __attribute__((ext_vector_type(8))) unsigned short u16x8;
typedef __attribute__((ext_vector_type(4))) unsigned short u16x4;

// 0.125 * log2(e): folded into Q projection so softmax is a bare v_exp_f32 (2^x)
#define QSCALE 0.18033688f

__device__ __forceinline__ unsigned short f2bf(float f) {
  union { float f; uint32_t u; } c; c.f = f;
  uint32_t u = c.u;
  return (unsigned short)((u + 0x7fffu + ((u >> 16) & 1u)) >> 16);
}

// async global->LDS, 16B per lane. LDS dest = wave-uniform base + lane*16.
__device__ __forceinline__ void gld16(const void* g, void* lds) {
  __builtin_amdgcn_global_load_lds(
      (const __attribute__((address_space(1))) void*)g,
      (__attribute__((address_space(3))) void*)lds,
      16, 0, 0);
}

// ---- fp32 -> bf16 convert, all 7 tensors in one launch ----
__global__ __launch_bounds__(256)
void cvt_all(const float* __restrict__ q, const float* __restrict__ k, const float* __restrict__ v,
             const float* __restrict__ Wq, const float* __restrict__ Wk,
             const float* __restrict__ Wv, const float* __restrict__ Wo,
             unsigned short* __restrict__ Xq, unsigned short* __restrict__ Xk,
             unsigned short* __restrict__ Xv,
             unsigned short* __restrict__ Wqb, unsigned short* __restrict__ Wkb,
             unsigned short* __restrict__ Wvb, unsigned short* __restrict__ Wob) {
  int blk = blockIdx.x;
  const float* in; unsigned short* out; int base;
  if (blk < 6144) {
    int ti = blk >> 11;
    in  = (ti == 0) ? q  : (ti == 1) ? k  : v;
    out = (ti == 0) ? Xq : (ti == 1) ? Xk : Xv;
    base = (blk & 2047) * 2048;
  } else {
    int ti = (blk - 6144) >> 9;
    in  = (ti == 0) ? Wq  : (ti == 1) ? Wk  : (ti == 2) ? Wv  : Wo;
    out = (ti == 0) ? Wqb : (ti == 1) ? Wkb : (ti == 2) ? Wvb : Wob;
    base = ((blk - 6144) & 511) * 2048;
  }
  int i = base + threadIdx.x * 8;
  float4 a = *(const float4*)(in + i);
  float4 b = *(const float4*)(in + i + 4);
  u16x8 o;
  o[0]=f2bf(a.x); o[1]=f2bf(a.y); o[2]=f2bf(a.z); o[3]=f2bf(a.w);
  o[4]=f2bf(b.x); o[5]=f2bf(b.y); o[6]=f2bf(b.z); o[7]=f2bf(b.w);
  *(u16x8*)(out + i) = o;
}

// ---- GEMM: Y[m][n] = sum_k X[m][k]*W[n][k] + bias[n] ----
// 128x128 tile, BK=64, 256 threads; hoisted LDS offsets + incremental pointers.
// LDS declared in caller (R9 bug: per-instantiation static __shared__ -> 96KB).
// MODE 0/1/3: operand-swapped MFMA (reg axis along Y cols -> vector stores).
// MODE 2: V -> permuted VT scatter.
// NOTE (R11): MODE-4 per-element atomic accumulate was an 8x write-path
// disaster (131MB WRITE_SIZE, 110us) — split-K via atomics is banned.
template <int MODE>
__device__ __forceinline__ void gemm_body(unsigned short* __restrict__ lA,
                                          unsigned short* __restrict__ lB,
                                          const unsigned short* __restrict__ X,
                                          const unsigned short* __restrict__ W,
                                          const float* __restrict__ bias,
                                          unsigned short* __restrict__ Yb,
                                          float* __restrict__ Yf,
                                          int rowBase, int colBase) {
  const int t = threadIdx.x;
  const int lane = t & 63, wave = t >> 6;
  const int cl = lane & 15, qd = lane >> 4;
  const int wm = wave >> 1, wn = wave & 1;
  const int srow = t >> 3, sslot = t & 7;

  // hoisted LDS read offsets (ushort indices), invariant across the k-loop
  int aoff[2][4], boff[2][4];
  #pragma unroll
  for (int ks = 0; ks < 2; ks++)
    #pragma unroll
    for (int i = 0; i < 4; i++) {
      int ra = wm * 64 + i * 16 + cl;
      aoff[ks][i] = ra * 64 + ((ks * 4 + qd) ^ (ra & 7)) * 8;
      int rb = wn * 64 + i * 16 + cl;
      boff[ks][i] = rb * 64 + ((ks * 4 + qd) ^ (rb & 7)) * 8;
    }
  // incremental staging pointers (advance 64 elems per k-step)
  const unsigned short* xp[4];
  const unsigned short* wp[4];
  #pragma unroll
  for (int i = 0; i < 4; i++) {
    int r = i * 32 + srow;
    int chunk = sslot ^ (r & 7);
    xp[i] = X + (size_t)(rowBase + r) * DMODEL + chunk * 8;
    wp[i] = W + (size_t)(colBase + r) * DMODEL + chunk * 8;
  }

  f32x4 zero = {0.f, 0.f, 0.f, 0.f};
  f32x4 acc[4][4];
  for (int mt = 0; mt < 4; mt++) for (int nt = 0; nt < 4; nt++) acc[mt][nt] = zero;

  for (int k0 = 0; k0 < DMODEL; k0 += 64) {
    __syncthreads();
    #pragma unroll
    for (int i = 0; i < 4; i++) {
      gld16(xp[i], (char*)lA + i * 4096 + wave * 1024);
      gld16(wp[i], (char*)lB + i * 4096 + wave * 1024);
      xp[i] += 64; wp[i] += 64;
    }
    __syncthreads();
    #pragma unroll
    for (int ks = 0; ks < 2; ks++) {
      bf16x8 af[4], bfr[4];
      #pragma unroll
      for (int mt = 0; mt < 4; mt++) af[mt] = *(const bf16x8*)&lA[aoff[ks][mt]];
      #pragma unroll
      for (int nt = 0; nt < 4; nt++) bfr[nt] = *(const bf16x8*)&lB[boff[ks][nt]];
      #pragma unroll
      for (int mt = 0; mt < 4; mt++)
        #pragma unroll
        for (int nt = 0; nt < 4; nt++) {
          if (MODE == 2)
            acc[mt][nt] = __builtin_amdgcn_mfma_f32_16x16x32_bf16(af[mt], bfr[nt], acc[mt][nt], 0, 0, 0);
          else  // swapped: D[m=Ycol][n=Yrow]
            acc[mt][nt] = __builtin_amdgcn_mfma_f32_16x16x32_bf16(bfr[nt], af[mt], acc[mt][nt], 0, 0, 0);
        }
    }
  }

  if (MODE == 2) {
    // original C/D layout: col(Ycol)=cl, row(Yrow)=qd*4+r
    // V projection -> permuted VT[(b*16+h)*64+d][s], s-nibbles reordered per
    // 32-half: l4<4 -> pos 2*l4 ; l4>=4 -> pos 2*(l4-4)+1
    #pragma unroll
    for (int mt = 0; mt < 4; mt++) {
      int row0 = rowBase + wm * 64 + mt * 16 + qd * 4;
      int bb = row0 >> 11;
      int s_in = row0 & 2047;
      int blk = s_in & ~63;
      int n4 = (s_in & 63) >> 2;
      int l4 = n4 & 7;
      int pos = 8 * (n4 >> 3) + ((l4 < 4) ? 2 * l4 : 2 * (l4 - 4) + 1);
      #pragma unroll
      for (int nt = 0; nt < 4; nt++) {
        int c = colBase + wn * 64 + nt * 16 + cl;
        float bv = bias[c];
        int hh = c >> 6, d = c & 63;
        u16x4 v;
        #pragma unroll
        for (int r = 0; r < 4; r++) v[r] = f2bf(acc[mt][nt][r] + bv);
        *(u16x4*)&Yb[(size_t)((bb * NHEAD + hh) * 64 + d) * SEQ + blk + pos * 4] = v;
      }
    }
  } else {
    // swapped C/D layout: n(Yrow)=cl, m(Ycol)=qd*4+r -> vector stores along cols
    #pragma unroll
    for (int nt = 0; nt < 4; nt++) {
      int col = colBase + wn * 64 + nt * 16 + qd * 4;
      f32x4 bv4 = *(const f32x4*)&bias[col];
      #pragma unroll
      for (int mt = 0; mt < 4; mt++) {
        int row = rowBase + wm * 64 + mt * 16 + cl;
        if (MODE == 3) {
          f32x4 v;
          #pragma unroll
          for (int r = 0; r < 4; r++) v[r] = acc[mt][nt][r] + bv4[r];
          *(f32x4*)&Yf[(size_t)row * DMODEL + col] = v;
        } else {
          u16x4 v;
          #pragma unroll
          for (int r = 0; r < 4; r++) {
            float x = acc[mt][nt][r] + bv4[r];
            v[r] = f2bf(MODE == 1 ? x * QSCALE : x);
          }
          *(u16x4*)&Yb[(size_t)row * DMODEL + col] = v;
        }
      }
    }
  }
}

// grid dim3(256,1,3): y-fastest linearization (by = id&31) so the 8 bx-blocks
// sharing an X panel have ids congruent mod 8 => same XCD; per-XCD L2 set ~3MB.
// __launch_bounds__(256,4): R9 measured VGPR=132 (caps at 3 blocks/CU);
// forcing <=128 VGPR buys a 4th block (LDS 32KB allows 5).
__global__ __launch_bounds__(256, 4)
void gemm_qkv(const unsigned short* __restrict__ Xq, const unsigned short* __restrict__ Xk,
              const unsigned short* __restrict__ Xv,
              const unsigned short* __restrict__ Wq, const unsigned short* __restrict__ Wk,
              const unsigned short* __restrict__ Wv,
              const float* __restrict__ bq, const float* __restrict__ bk,
              const float* __restrict__ bv,
              unsigned short* __restrict__ Q, unsigned short* __restrict__ K,
              unsigned short* __restrict__ VT) {
  __shared__ unsigned short lA[128 * 64];   // 16 KB — shared by all MODE paths
  __shared__ unsigned short lB[128 * 64];   // 16 KB
  int id = blockIdx.x;
  int by = id & 31, bx = id >> 5;
  int z = blockIdx.z;
  if (z == 0)      gemm_body<1>(lA, lB, Xq, Wq, bq, Q,  nullptr, by * 128, bx * 128);
  else if (z == 1) gemm_body<0>(lA, lB, Xk, Wk, bk, K,  nullptr, by * 128, bx * 128);
  else             gemm_body<2>(lA, lB, Xv, Wv, bv, VT, nullptr, by * 128, bx * 128);
}

__global__ __launch_bounds__(256)
void gemm_out(const unsigned short* __restrict__ CTX, const unsigned short* __restrict__ Wo,
              const float* __restrict__ bo, float* __restrict__ out) {
  __shared__ unsigned short lA[128 * 64];
  __shared__ unsigned short lB[128 * 64];
  int id = blockIdx.x;
  int by = id & 31, bx = id >> 5;
  gemm_body<3>(lA, lB, CTX, Wo, bo, nullptr, out, by * 128, bx * 128);
}

// ---- flash attention, transposed: S^T = K Q^T, O^T = V^T P^T ----
// R8 body. XCD swizzle: all 16 qt-blocks of one (h,b) land on one XCD so K/V
// tiles are fetched once per XCD (R10: FETCH 69.7 -> 12.3 MB).
__global__ __launch_bounds__(256)
void attn(const unsigned short* __restrict__ Q, const unsigned short* __restrict__ K,
          const unsigned short* __restrict__ VT, unsigned short* __restrict__ CTX) {
  __shared__ unsigned short lK[2 * 64 * 64];  // 16 KB (Q staged here first)
  __shared__ unsigned short lV[2 * 64 * 64];  // 16 KB, permuted VT tiles
  const int t = threadIdx.x, lane = t & 63, wave = t >> 6;
  const int cl = lane & 15, qd = lane >> 4;
  // XCD-aware remap: flat -> (xcd = flat&7, loc); (h,b) = p = xcd*4 + loc>>4
  const int flat = blockIdx.x + 16 * blockIdx.y + 256 * blockIdx.z;
  const int loc = flat >> 3;
  const int p = (flat & 7) * 4 + (loc >> 4);
  const int qt = loc & 15, h = p & 15, b = p >> 4;
  const int srow = t >> 3, sslot = t & 7;

  // stage 128 Q rows into lK halves
  #pragma unroll
  for (int half = 0; half < 2; half++)
    #pragma unroll
    for (int i = 0; i < 2; i++) {
      int r = i * 32 + srow;
      int chunk = sslot ^ (r & 7);
      gld16(Q + (size_t)(b * SEQ + qt * 128 + half * 64 + r) * DMODEL + h * 64 + chunk * 8,
            (char*)lK + half * 8192 + i * 4096 + wave * 1024);
    }
  __syncthreads();
  bf16x8 qf[2][2];
  #pragma unroll
  for (int qg = 0; qg < 2; qg++)
    #pragma unroll
    for (int ks = 0; ks < 2; ks++) {
      int r = wave * 16 + cl;
      int slot = (ks * 4 + qd) ^ (r & 7);
      qf[qg][ks] = *(const bf16x8*)&lK[qg * 4096 + r * 64 + slot * 8];
    }
  __syncthreads();  // all waves done reading Q before K staging overwrites

  // hoisted LDS read offsets (kt-invariant)
  int ka[8], va[8];
  #pragma unroll
  for (int ks = 0; ks < 2; ks++)
    #pragma unroll
    for (int nt = 0; nt < 4; nt++) {
      int rk = nt * 16 + cl;
      ka[ks * 4 + nt] = rk * 64 + ((ks * 4 + qd) ^ (rk & 7)) * 8;
    }
  #pragma unroll
  for (int ntp = 0; ntp < 2; ntp++)
    #pragma unroll
    for (int dt = 0; dt < 4; dt++) {
      int d = dt * 16 + cl;
      va[ntp * 4 + dt] = d * 64 + ((4 * ntp + qd) ^ (d & 7)) * 8;
    }

  // stage K/V tile 0 into buffer 0; init incremental prefetch pointers
  const unsigned short* kp[2];
  const unsigned short* vp[2];
  #pragma unroll
  for (int i = 0; i < 2; i++) {
    int r = i * 32 + srow;
    int chunk = sslot ^ (r & 7);
    kp[i] = K + (size_t)(b * SEQ + r) * DMODEL + h * 64 + chunk * 8;
    vp[i] = VT + (size_t)((b * NHEAD + h) * 64 + r) * SEQ + chunk * 8;
    gld16(kp[i], (char*)lK + i * 4096 + wave * 1024);
    gld16(vp[i], (char*)lV + i * 4096 + wave * 1024);
    kp[i] += 64 * DMODEL; vp[i] += 64;
  }

  f32x4 zero = {0.f, 0.f, 0.f, 0.f};
  f32x4 o[2][4];     // o[qg][dt][r] = O^T[d=dt*16+qd*4+r][q=cl]
  f32x4 osum[2];     // row-sum via ones-MFMA
  #pragma unroll
  for (int qg = 0; qg < 2; qg++) {
    #pragma unroll
    for (int dt = 0; dt < 4; dt++) o[qg][dt] = zero;
    osum[qg] = zero;
  }
  bf16x8 ones;
  #pragma unroll
  for (int j = 0; j < 8; j++) ones[j] = (__bf16)1.0f;

  #pragma unroll 2
  for (int kt = 0; kt < SEQ / 64; kt++) {
    const int cb = (kt & 1) * 4096;
    __syncthreads();  // tile kt's loads drained; other buffer free
    if (kt + 1 < SEQ / 64) {
      const int nb = ((kt + 1) & 1) * 8192;
      #pragma unroll
      for (int i = 0; i < 2; i++) {
        gld16(kp[i], (char*)lK + nb + i * 4096 + wave * 1024);
        gld16(vp[i], (char*)lV + nb + i * 4096 + wave * 1024);
        kp[i] += 64 * DMODEL; vp[i] += 64;
      }
    }

    // S^T[kv][q]: A = K rows, B = qf; kf shared across both q-groups
    f32x4 sc[2][4];
    #pragma unroll
    for (int qg = 0; qg < 2; qg++)
      #pragma unroll
      for (int nt = 0; nt < 4; nt++) sc[qg][nt] = zero;
    #pragma unroll
    for (int ks = 0; ks < 2; ks++)
      #pragma unroll
      for (int nt = 0; nt < 4; nt++) {
        bf16x8 kf = *(const bf16x8*)&lK[cb + ka[ks * 4 + nt]];
        sc[0][nt] = __builtin_amdgcn_mfma_f32_16x16x32_bf16(kf, qf[0][ks], sc[0][nt], 0, 0, 0);
        sc[1][nt] = __builtin_amdgcn_mfma_f32_16x16x32_bf16(kf, qf[1][ks], sc[1][nt], 0, 0, 0);
      }

    // P^T = 2^(S^T); pack straight to bf16 frags
    bf16x8 pb[2][2];
    #pragma unroll
    for (int qg = 0; qg < 2; qg++)
      #pragma unroll
      for (int ntp = 0; ntp < 2; ntp++) {
        bf16x8 x;
        #pragma unroll
        for (int j = 0; j < 4; j++)
          x[j] = (__bf16)__builtin_amdgcn_exp2f(sc[qg][2 * ntp][j]);
        #pragma unroll
        for (int j = 0; j < 4; j++)
          x[4 + j] = (__bf16)__builtin_amdgcn_exp2f(sc[qg][2 * ntp + 1][j]);
        pb[qg][ntp] = x;
      }

    // row-sum on the matrix pipe
    #pragma unroll
    for (int qg = 0; qg < 2; qg++) {
      osum[qg] = __builtin_amdgcn_mfma_f32_16x16x32_bf16(ones, pb[qg][0], osum[qg], 0, 0, 0);
      osum[qg] = __builtin_amdgcn_mfma_f32_16x16x32_bf16(ones, pb[qg][1], osum[qg], 0, 0, 0);
    }

    // O^T += V^T P^T; vf shared across both q-groups
    #pragma unroll
    for (int ntp = 0; ntp < 2; ntp++)
      #pragma unroll
      for (int dt = 0; dt < 4; dt++) {
        bf16x8 vf = *(const bf16x8*)&lV[cb + va[ntp * 4 + dt]];
        o[0][dt] = __builtin_amdgcn_mfma_f32_16x16x32_bf16(vf, pb[0][ntp], o[0][dt], 0, 0, 0);
        o[1][dt] = __builtin_amdgcn_mfma_f32_16x16x32_bf16(vf, pb[1][ntp], o[1][dt], 0, 0, 0);
      }
  }

  // epilogue: every lane holds its q-column's sum in osum[qg][0]
  #pragma unroll
  for (int qg = 0; qg < 2; qg++) {
    float inv = 1.f / osum[qg][0];
    int row = b * SEQ + qt * 128 + qg * 64 + wave * 16 + cl;
    #pragma unroll
    for (int dt = 0; dt < 4; dt++) {
      u16x4 v;
      #pragma unroll
      for (int r = 0; r < 4; r++) v[r] = f2bf(o[qg][dt][r] * inv);
      *(u16x4*)&CTX[(size_t)row * DMODEL + h * 64 + dt * 16 + qd * 4] = v;
    }
  }
}

extern "C" void kernel_launch(void* const* d_in, const int* in_sizes, int n_in,
                              void* d_out, int out_size, void* d_ws, size_t ws_size,
                              hipStream_t stream) {
  const float* q  = (const float*)d_in[0];
  const float* k  = (const float*)d_in[1];
  const float* v  = (const float*)d_in[2];
  const float* Wq = (const float*)d_in[3]; const float* bq = (const float*)d_in[4];
  const float* Wk = (const float*)d_in[5]; const float* bk = (const float*)d_in[6];
  const float* Wv = (const float*)d_in[7]; const float* bv = (const float*)d_in[8];
  const float* Wo = (const float*)d_in[9]; const float* bo = (const float*)d_in[10];
  float* out = (float*)d_out;

  char* ws = (char*)d_ws;
  const size_t MB = 1u << 20;
  // Liveness: Wob kept at +70MB (R4-R6 NaN was an Opart->Wob clobber)
  unsigned short* Xq  = (unsigned short*)(ws + 0 * MB);
  unsigned short* Xk  = (unsigned short*)(ws + 8 * MB);
  unsigned short* Xv  = (unsigned short*)(ws + 16 * MB);
  unsigned short* Wqb = (unsigned short*)(ws + 24 * MB);
  unsigned short* Wkb = (unsigned short*)(ws + 26 * MB);
  unsigned short* Wvb = (unsigned short*)(ws + 28 * MB);
  unsigned short* Wob = (unsigned short*)(ws + 70 * MB);
  unsigned short* Qp  = (unsigned short*)(ws + 32 * MB);
  unsigned short* Kp  = (unsigned short*)(ws + 40 * MB);
  unsigned short* VT  = (unsigned short*)(ws + 48 * MB);
  unsigned short* CTX = (unsigned short*)(ws + 56 * MB);

  cvt_all<<<8192, 256, 0, stream>>>(q, k, v, Wq, Wk, Wv, Wo,
                                    Xq, Xk, Xv, Wqb, Wkb, Wvb, Wob);

  gemm_qkv<<<dim3(256, 1, 3), 256, 0, stream>>>(
      Xq, Xk, Xv, Wqb, Wkb, Wvb, bq, bk, bv, Qp, Kp, VT);

  attn<<<dim3(SEQ / 128, NHEAD, BATCH), 256, 0, stream>>>(Qp, Kp, VT, CTX);

  gemm_out<<<256, 256, 0, stream>>>(CTX, Wob, bo, out);
}

// Round 13
// 215.017 us; speedup vs baseline: 1.4460x; 1.1427x over previous
//
#include <hip/hip_runtime.h>
#include <stdint.h>

// ---- problem constants ----
#define BATCH 2
#define SEQ   2048
#define NHEAD 16
#define DK    64
#define DMODEL 1024
#define MROWS (BATCH*SEQ)   // 4096

typedef __attribute__((ext_vector_type(8))) __bf16 bf16x8;
typedef __attribute__((ext_vector_type(4))) float f32x4;
typedef __attribute__((ext_vector_type(8))) unsigned short u16x8;
typedef __attribute__((ext_vector_type(4))) unsigned short u16x4;

// 0.125 * log2(e): folded into Q projection so softmax is a bare v_exp_f32 (2^x)
#define QSCALE 0.18033688f

__device__ __forceinline__ unsigned short f2bf(float f) {
  union { float f; uint32_t u; } c; c.f = f;
  uint32_t u = c.u;
  return (unsigned short)((u + 0x7fffu + ((u >> 16) & 1u)) >> 16);
}

// async global->LDS, 16B per lane. LDS dest = wave-uniform base + lane*16.
__device__ __forceinline__ void gld16(const void* g, void* lds) {
  __builtin_amdgcn_global_load_lds(
      (const __attribute__((address_space(1))) void*)g,
      (__attribute__((address_space(3))) void*)lds,
      16, 0, 0);
}

// ---- fp32 -> bf16 convert, all 7 tensors in one launch ----
__global__ __launch_bounds__(256)
void cvt_all(const float* __restrict__ q, const float* __restrict__ k, const float* __restrict__ v,
             const float* __restrict__ Wq, const float* __restrict__ Wk,
             const float* __restrict__ Wv, const float* __restrict__ Wo,
             unsigned short* __restrict__ Xq, unsigned short* __restrict__ Xk,
             unsigned short* __restrict__ Xv,
             unsigned short* __restrict__ Wqb, unsigned short* __restrict__ Wkb,
             unsigned short* __restrict__ Wvb, unsigned short* __restrict__ Wob) {
  int blk = blockIdx.x;
  const float* in; unsigned short* out; int base;
  if (blk < 6144) {
    int ti = blk >> 11;
    in  = (ti == 0) ? q  : (ti == 1) ? k  : v;
    out = (ti == 0) ? Xq : (ti == 1) ? Xk : Xv;
    base = (blk & 2047) * 2048;
  } else {
    int ti = (blk - 6144) >> 9;
    in  = (ti == 0) ? Wq  : (ti == 1) ? Wk  : (ti == 2) ? Wv  : Wo;
    out = (ti == 0) ? Wqb : (ti == 1) ? Wkb : (ti == 2) ? Wvb : Wob;
    base = ((blk - 6144) & 511) * 2048;
  }
  int i = base + threadIdx.x * 8;
  float4 a = *(const float4*)(in + i);
  float4 b = *(const float4*)(in + i + 4);
  u16x8 o;
  o[0]=f2bf(a.x); o[1]=f2bf(a.y); o[2]=f2bf(a.z); o[3]=f2bf(a.w);
  o[4]=f2bf(b.x); o[5]=f2bf(b.y); o[6]=f2bf(b.z); o[7]=f2bf(b.w);
  *(u16x8*)(out + i) = o;
}

// ---- GEMM: Y[m][n] = sum_k X[m][k]*W[n][k] + bias[n] ----
// (MT*32)x128 tile (MT=4: 128x128; MT=2: 64x128), BK=64, 256 threads.
// Hoisted LDS offsets + incremental staging pointers. LDS declared in caller
// (R9 bug: per-instantiation static __shared__ -> 96KB).
// MODE 0/1/3: operand-swapped MFMA (reg axis along Y cols -> vector stores).
// MODE 2: V -> permuted VT scatter (MT=4 only).
// R11 lesson: per-element atomic accumulate epilogues are banned (8x writes).
// R12 lesson: no forced launch_bounds (VGPR=64 -> 157MB scratch spills).
template <int MODE, int MT>
__device__ __forceinline__ void gemm_body(unsigned short* __restrict__ lA,
                                          unsigned short* __restrict__ lB,
                                          const unsigned short* __restrict__ X,
                                          const unsigned short* __restrict__ W,
                                          const float* __restrict__ bias,
                                          unsigned short* __restrict__ Yb,
                                          float* __restrict__ Yf,
                                          int rowBase, int colBase) {
  const int t = threadIdx.x;
  const int lane = t & 63, wave = t >> 6;
  const int cl = lane & 15, qd = lane >> 4;
  const int wm = wave >> 1, wn = wave & 1;
  const int srow = t >> 3, sslot = t & 7;

  // hoisted LDS read offsets (ushort indices), invariant across the k-loop
  int aoff[2][MT], boff[2][4];
  #pragma unroll
  for (int ks = 0; ks < 2; ks++) {
    #pragma unroll
    for (int i = 0; i < MT; i++) {
      int ra = wm * (MT * 16) + i * 16 + cl;
      aoff[ks][i] = ra * 64 + ((ks * 4 + qd) ^ (ra & 7)) * 8;
    }
    #pragma unroll
    for (int i = 0; i < 4; i++) {
      int rb = wn * 64 + i * 16 + cl;
      boff[ks][i] = rb * 64 + ((ks * 4 + qd) ^ (rb & 7)) * 8;
    }
  }
  // incremental staging pointers (advance 64 elems per k-step)
  const unsigned short* xp[MT];
  const unsigned short* wp[4];
  #pragma unroll
  for (int i = 0; i < MT; i++) {
    int r = i * 32 + srow;
    int chunk = sslot ^ (r & 7);
    xp[i] = X + (size_t)(rowBase + r) * DMODEL + chunk * 8;
  }
  #pragma unroll
  for (int i = 0; i < 4; i++) {
    int r = i * 32 + srow;
    int chunk = sslot ^ (r & 7);
    wp[i] = W + (size_t)(colBase + r) * DMODEL + chunk * 8;
  }

  f32x4 zero = {0.f, 0.f, 0.f, 0.f};
  f32x4 acc[MT][4];
  for (int mt = 0; mt < MT; mt++) for (int nt = 0; nt < 4; nt++) acc[mt][nt] = zero;

  for (int k0 = 0; k0 < DMODEL; k0 += 64) {
    __syncthreads();
    #pragma unroll
    for (int i = 0; i < MT; i++) {
      gld16(xp[i], (char*)lA + i * 4096 + wave * 1024);
      xp[i] += 64;
    }
    #pragma unroll
    for (int i = 0; i < 4; i++) {
      gld16(wp[i], (char*)lB + i * 4096 + wave * 1024);
      wp[i] += 64;
    }
    __syncthreads();
    #pragma unroll
    for (int ks = 0; ks < 2; ks++) {
      bf16x8 af[MT], bfr[4];
      #pragma unroll
      for (int mt = 0; mt < MT; mt++) af[mt] = *(const bf16x8*)&lA[aoff[ks][mt]];
      #pragma unroll
      for (int nt = 0; nt < 4; nt++) bfr[nt] = *(const bf16x8*)&lB[boff[ks][nt]];
      #pragma unroll
      for (int mt = 0; mt < MT; mt++)
        #pragma unroll
        for (int nt = 0; nt < 4; nt++) {
          if (MODE == 2)
            acc[mt][nt] = __builtin_amdgcn_mfma_f32_16x16x32_bf16(af[mt], bfr[nt], acc[mt][nt], 0, 0, 0);
          else  // swapped: D[m=Ycol][n=Yrow]
            acc[mt][nt] = __builtin_amdgcn_mfma_f32_16x16x32_bf16(bfr[nt], af[mt], acc[mt][nt], 0, 0, 0);
        }
    }
  }

  if (MODE == 2) {
    // original C/D layout: col(Ycol)=cl, row(Yrow)=qd*4+r
    // V projection -> permuted VT[(b*16+h)*64+d][s], s-nibbles reordered per
    // 32-half: l4<4 -> pos 2*l4 ; l4>=4 -> pos 2*(l4-4)+1
    #pragma unroll
    for (int mt = 0; mt < MT; mt++) {
      int row0 = rowBase + wm * (MT * 16) + mt * 16 + qd * 4;
      int bb = row0 >> 11;
      int s_in = row0 & 2047;
      int blk = s_in & ~63;
      int n4 = (s_in & 63) >> 2;
      int l4 = n4 & 7;
      int pos = 8 * (n4 >> 3) + ((l4 < 4) ? 2 * l4 : 2 * (l4 - 4) + 1);
      #pragma unroll
      for (int nt = 0; nt < 4; nt++) {
        int c = colBase + wn * 64 + nt * 16 + cl;
        float bv = bias[c];
        int hh = c >> 6, d = c & 63;
        u16x4 v;
        #pragma unroll
        for (int r = 0; r < 4; r++) v[r] = f2bf(acc[mt][nt][r] + bv);
        *(u16x4*)&Yb[(size_t)((bb * NHEAD + hh) * 64 + d) * SEQ + blk + pos * 4] = v;
      }
    }
  } else {
    // swapped C/D layout: n(Yrow)=cl, m(Ycol)=qd*4+r -> vector stores along cols
    #pragma unroll
    for (int nt = 0; nt < 4; nt++) {
      int col = colBase + wn * 64 + nt * 16 + qd * 4;
      f32x4 bv4 = *(const f32x4*)&bias[col];
      #pragma unroll
      for (int mt = 0; mt < MT; mt++) {
        int row = rowBase + wm * (MT * 16) + mt * 16 + cl;
        if (MODE == 3) {
          f32x4 v;
          #pragma unroll
          for (int r = 0; r < 4; r++) v[r] = acc[mt][nt][r] + bv4[r];
          *(f32x4*)&Yf[(size_t)row * DMODEL + col] = v;
        } else {
          u16x4 v;
          #pragma unroll
          for (int r = 0; r < 4; r++) {
            float x = acc[mt][nt][r] + bv4[r];
            v[r] = f2bf(MODE == 1 ? x * QSCALE : x);
          }
          *(u16x4*)&Yb[(size_t)row * DMODEL + col] = v;
        }
      }
    }
  }
}

// grid dim3(256,1,3): y-fastest linearization (by = id&31) so the 8 bx-blocks
// sharing an X panel have ids congruent mod 8 => same XCD; per-XCD L2 set ~3MB.
__global__ __launch_bounds__(256)
void gemm_qkv(const unsigned short* __restrict__ Xq, const unsigned short* __restrict__ Xk,
              const unsigned short* __restrict__ Xv,
              const unsigned short* __restrict__ Wq, const unsigned short* __restrict__ Wk,
              const unsigned short* __restrict__ Wv,
              const float* __restrict__ bq, const float* __restrict__ bk,
              const float* __restrict__ bv,
              unsigned short* __restrict__ Q, unsigned short* __restrict__ K,
              unsigned short* __restrict__ VT) {
  __shared__ unsigned short lA[128 * 64];   // 16 KB — shared by all MODE paths
  __shared__ unsigned short lB[128 * 64];   // 16 KB
  int id = blockIdx.x;
  int by = id & 31, bx = id >> 5;
  int z = blockIdx.z;
  if (z == 0)      gemm_body<1, 4>(lA, lB, Xq, Wq, bq, Q,  nullptr, by * 128, bx * 128);
  else if (z == 1) gemm_body<0, 4>(lA, lB, Xk, Wk, bk, K,  nullptr, by * 128, bx * 128);
  else             gemm_body<2, 4>(lA, lB, Xv, Wv, bv, VT, nullptr, by * 128, bx * 128);
}

// grid 512: 64x128 tiles (MT=2) -> 2 blocks/CU (R10's 256-block version was a
// 1-block/CU occupancy floor). Plain stores, no atomics. Panel-sharers
// (same by, ids differing by 64) are congruent mod 8 => same XCD.
__global__ __launch_bounds__(256)
void gemm_out(const unsigned short* __restrict__ CTX, const unsigned short* __restrict__ Wo,
              const float* __restrict__ bo, float* __restrict__ out) {
  __shared__ unsigned short lA[64 * 64];    // 8 KB (MT=2)
  __shared__ unsigned short lB[128 * 64];   // 16 KB
  int id = blockIdx.x;
  int by = id & 63, bx = id >> 6;
  gemm_body<3, 2>(lA, lB, CTX, Wo, bo, nullptr, out, by * 64, bx * 128);
}

// ---- flash attention, transposed: S^T = K Q^T, O^T = V^T P^T ----
// R8 body. XCD swizzle: all 16 qt-blocks of one (h,b) land on one XCD so K/V
// tiles are fetched once per XCD (R10: FETCH 69.7 -> 12.3 MB).
__global__ __launch_bounds__(256)
void attn(const unsigned short* __restrict__ Q, const unsigned short* __restrict__ K,
          const unsigned short* __restrict__ VT, unsigned short* __restrict__ CTX) {
  __shared__ unsigned short lK[2 * 64 * 64];  // 16 KB (Q staged here first)
  __shared__ unsigned short lV[2 * 64 * 64];  // 16 KB, permuted VT tiles
  const int t = threadIdx.x, lane = t & 63, wave = t >> 6;
  const int cl = lane & 15, qd = lane >> 4;
  // XCD-aware remap: flat -> (xcd = flat&7, loc); (h,b) = p = xcd*4 + loc>>4
  const int flat = blockIdx.x + 16 * blockIdx.y + 256 * blockIdx.z;
  const int loc = flat >> 3;
  const int p = (flat & 7) * 4 + (loc >> 4);
  const int qt = loc & 15, h = p & 15, b = p >> 4;
  const int srow = t >> 3, sslot = t & 7;

  // stage 128 Q rows into lK halves
  #pragma unroll
  for (int half = 0; half < 2; half++)
    #pragma unroll
    for (int i = 0; i < 2; i++) {
      int r = i * 32 + srow;
      int chunk = sslot ^ (r & 7);
      gld16(Q + (size_t)(b * SEQ + qt * 128 + half * 64 + r) * DMODEL + h * 64 + chunk * 8,
            (char*)lK + half * 8192 + i * 4096 + wave * 1024);
    }
  __syncthreads();
  bf16x8 qf[2][2];
  #pragma unroll
  for (int qg = 0; qg < 2; qg++)
    #pragma unroll
    for (int ks = 0; ks < 2; ks++) {
      int r = wave * 16 + cl;
      int slot = (ks * 4 + qd) ^ (r & 7);
      qf[qg][ks] = *(const bf16x8*)&lK[qg * 4096 + r * 64 + slot * 8];
    }
  __syncthreads();  // all waves done reading Q before K staging overwrites

  // hoisted LDS read offsets (kt-invariant)
  int ka[8], va[8];
  #pragma unroll
  for (int ks = 0; ks < 2; ks++)
    #pragma unroll
    for (int nt = 0; nt < 4; nt++) {
      int rk = nt * 16 + cl;
      ka[ks * 4 + nt] = rk * 64 + ((ks * 4 + qd) ^ (rk & 7)) * 8;
    }
  #pragma unroll
  for (int ntp = 0; ntp < 2; ntp++)
    #pragma unroll
    for (int dt = 0; dt < 4; dt++) {
      int d = dt * 16 + cl;
      va[ntp * 4 + dt] = d * 64 + ((4 * ntp + qd) ^ (d & 7)) * 8;
    }

  // stage K/V tile 0 into buffer 0; init incremental prefetch pointers
  const unsigned short* kp[2];
  const unsigned short* vp[2];
  #pragma unroll
  for (int i = 0; i < 2; i++) {
    int r = i * 32 + srow;
    int chunk = sslot ^ (r & 7);
    kp[i] = K + (size_t)(b * SEQ + r) * DMODEL + h * 64 + chunk * 8;
    vp[i] = VT + (size_t)((b * NHEAD + h) * 64 + r) * SEQ + chunk * 8;
    gld16(kp[i], (char*)lK + i * 4096 + wave * 1024);
    gld16(vp[i], (char*)lV + i * 4096 + wave * 1024);
    kp[i] += 64 * DMODEL; vp[i] += 64;
  }

  f32x4 zero = {0.f, 0.f, 0.f, 0.f};
  f32x4 o[2][4];     // o[qg][dt][r] = O^T[d=dt*16+qd*4+r][q=cl]
  f32x4 osum[2];     // row-sum via ones-MFMA
  #pragma unroll
  for (int qg = 0; qg < 2; qg++) {
    #pragma unroll
    for (int dt = 0; dt < 4; dt++) o[qg][dt] = zero;
    osum[qg] = zero;
  }
  bf16x8 ones;
  #pragma unroll
  for (int j = 0; j < 8; j++) ones[j] = (__bf16)1.0f;

  #pragma unroll 2
  for (int kt = 0; kt < SEQ / 64; kt++) {
    const int cb = (kt & 1) * 4096;
    __syncthreads();  // tile kt's loads drained; other buffer free
    if (kt + 1 < SEQ / 64) {
      const int nb = ((kt + 1) & 1) * 8192;
      #pragma unroll
      for (int i = 0; i < 2; i++) {
        gld16(kp[i], (char*)lK + nb + i * 4096 + wave * 1024);
        gld16(vp[i], (char*)lV + nb + i * 4096 + wave * 1024);
        kp[i] += 64 * DMODEL; vp[i] += 64;
      }
    }

    // S^T[kv][q]: A = K rows, B = qf; kf shared across both q-groups
    f32x4 sc[2][4];
    #pragma unroll
    for (int qg = 0; qg < 2; qg++)
      #pragma unroll
      for (int nt = 0; nt < 4; nt++) sc[qg][nt] = zero;
    #pragma unroll
    for (int ks = 0; ks < 2; ks++)
      #pragma unroll
      for (int nt = 0; nt < 4; nt++) {
        bf16x8 kf = *(const bf16x8*)&lK[cb + ka[ks * 4 + nt]];
        sc[0][nt] = __builtin_amdgcn_mfma_f32_16x16x32_bf16(kf, qf[0][ks], sc[0][nt], 0, 0, 0);
        sc[1][nt] = __builtin_amdgcn_mfma_f32_16x16x32_bf16(kf, qf[1][ks], sc[1][nt], 0, 0, 0);
      }

    // P^T = 2^(S^T); pack straight to bf16 frags
    bf16x8 pb[2][2];
    #pragma unroll
    for (int qg = 0; qg < 2; qg++)
      #pragma unroll
      for (int ntp = 0; ntp < 2; ntp++) {
        bf16x8 x;
        #pragma unroll
        for (int j = 0; j < 4; j++)
          x[j] = (__bf16)__builtin_amdgcn_exp2f(sc[qg][2 * ntp][j]);
        #pragma unroll
        for (int j = 0; j < 4; j++)
          x[4 + j] = (__bf16)__builtin_amdgcn_exp2f(sc[qg][2 * ntp + 1][j]);
        pb[qg][ntp] = x;
      }

    // row-sum on the matrix pipe
    #pragma unroll
    for (int qg = 0; qg < 2; qg++) {
      osum[qg] = __builtin_amdgcn_mfma_f32_16x16x32_bf16(ones, pb[qg][0], osum[qg], 0, 0, 0);
      osum[qg] = __builtin_amdgcn_mfma_f32_16x16x32_bf16(ones, pb[qg][1], osum[qg], 0, 0, 0);
    }

    // O^T += V^T P^T; vf shared across both q-groups
    #pragma unroll
    for (int ntp = 0; ntp < 2; ntp++)
      #pragma unroll
      for (int dt = 0; dt < 4; dt++) {
        bf16x8 vf = *(const bf16x8*)&lV[cb + va[ntp * 4 + dt]];
        o[0][dt] = __builtin_amdgcn_mfma_f32_16x16x32_bf16(vf, pb[0][ntp], o[0][dt], 0, 0, 0);
        o[1][dt] = __builtin_amdgcn_mfma_f32_16x16x32_bf16(vf, pb[1][ntp], o[1][dt], 0, 0, 0);
      }
  }

  // epilogue: every lane holds its q-column's sum in osum[qg][0]
  #pragma unroll
  for (int qg = 0; qg < 2; qg++) {
    float inv = 1.f / osum[qg][0];
    int row = b * SEQ + qt * 128 + qg * 64 + wave * 16 + cl;
    #pragma unroll
    for (int dt = 0; dt < 4; dt++) {
      u16x4 v;
      #pragma unroll
      for (int r = 0; r < 4; r++) v[r] = f2bf(o[qg][dt][r] * inv);
      *(u16x4*)&CTX[(size_t)row * DMODEL + h * 64 + dt * 16 + qd * 4] = v;
    }
  }
}

extern "C" void kernel_launch(void* const* d_in, const int* in_sizes, int n_in,
                              void* d_out, int out_size, void* d_ws, size_t ws_size,
                              hipStream_t stream) {
  const float* q  = (const float*)d_in[0];
  const float* k  = (const float*)d_in[1];
  const float* v  = (const float*)d_in[2];
  const float* Wq = (const float*)d_in[3]; const float* bq = (const float*)d_in[4];
  const float* Wk = (const float*)d_in[5]; const float* bk = (const float*)d_in[6];
  const float* Wv = (const float*)d_in[7]; const float* bv = (const float*)d_in[8];
  const float* Wo = (const float*)d_in[9]; const float* bo = (const float*)d_in[10];
  float* out = (float*)d_out;

  char* ws = (char*)d_ws;
  const size_t MB = 1u << 20;
  // Liveness: Wob kept at +70MB (R4-R6 NaN was an Opart->Wob clobber)
  unsigned short* Xq  = (unsigned short*)(ws + 0 * MB);
  unsigned short* Xk  = (unsigned short*)(ws + 8 * MB);
  unsigned short* Xv  = (unsigned short*)(ws + 16 * MB);
  unsigned short* Wqb = (unsigned short*)(ws + 24 * MB);
  unsigned short* Wkb = (unsigned short*)(ws + 26 * MB);
  unsigned short* Wvb = (unsigned short*)(ws + 28 * MB);
  unsigned short* Wob = (unsigned short*)(ws + 70 * MB);
  unsigned short* Qp  = (unsigned short*)(ws + 32 * MB);
  unsigned short* Kp  = (unsigned short*)(ws + 40 * MB);
  unsigned short* VT  = (unsigned short*)(ws + 48 * MB);
  unsigned short* CTX = (unsigned short*)(ws + 56 * MB);

  cvt_all<<<8192, 256, 0, stream>>>(q, k, v, Wq, Wk, Wv, Wo,
                                    Xq, Xk, Xv, Wqb, Wkb, Wvb, Wob);

  gemm_qkv<<<dim3(256, 1, 3), 256, 0, stream>>>(
      Xq, Xk, Xv, Wqb, Wkb, Wvb, bq, bk, bv, Qp, Kp, VT);

  attn<<<dim3(SEQ / 128, NHEAD, BATCH), 256, 0, stream>>>(Qp, Kp, VT, CTX);

  gemm_out<<<512, 256, 0, stream>>>(CTX, Wob, bo, out);
}

// Round 14
// 208.330 us; speedup vs baseline: 1.4924x; 1.0321x over previous
//
#include <hip/hip_runtime.h>
#include <stdint.h>

// ---- problem constants ----
#define BATCH 2
#define SEQ   2048
#define NHEAD 16
#define DK    64
#define DMODEL 1024
#define MROWS (BATCH*SEQ)   // 4096

typedef __attribute__((ext_vector_type(8))) __bf16 bf16x8;
typedef __attribute__((ext_vector_type(4))) float f32x4;
typedef __attribute__((ext_vector_type(8))) unsigned short u16x8;
typedef __attribute__((ext_vector_type(4))) unsigned short u16x4;

// 0.125 * log2(e): folded into Q projection so softmax is a bare v_exp_f32 (2^x)
#define QSCALE 0.18033688f

__device__ __forceinline__ unsigned short f2bf(float f) {
  union { float f; uint32_t u; } c; c.f = f;
  uint32_t u = c.u;
  return (unsigned short)((u + 0x7fffu + ((u >> 16) & 1u)) >> 16);
}

// async global->LDS, 16B per lane. LDS dest = wave-uniform base + lane*16.
__device__ __forceinline__ void gld16(const void* g, void* lds) {
  __builtin_amdgcn_global_load_lds(
      (const __attribute__((address_space(1))) void*)g,
      (__attribute__((address_space(3))) void*)lds,
      16, 0, 0);
}

// ---- fp32 -> bf16 convert, all 7 tensors in one launch ----
__global__ __launch_bounds__(256)
void cvt_all(const float* __restrict__ q, const float* __restrict__ k, const float* __restrict__ v,
             const float* __restrict__ Wq, const float* __restrict__ Wk,
             const float* __restrict__ Wv, const float* __restrict__ Wo,
             unsigned short* __restrict__ Xq, unsigned short* __restrict__ Xk,
             unsigned short* __restrict__ Xv,
             unsigned short* __restrict__ Wqb, unsigned short* __restrict__ Wkb,
             unsigned short* __restrict__ Wvb, unsigned short* __restrict__ Wob) {
  int blk = blockIdx.x;
  const float* in; unsigned short* out; int base;
  if (blk < 6144) {
    int ti = blk >> 11;
    in  = (ti == 0) ? q  : (ti == 1) ? k  : v;
    out = (ti == 0) ? Xq : (ti == 1) ? Xk : Xv;
    base = (blk & 2047) * 2048;
  } else {
    int ti = (blk - 6144) >> 9;
    in  = (ti == 0) ? Wq  : (ti == 1) ? Wk  : (ti == 2) ? Wv  : Wo;
    out = (ti == 0) ? Wqb : (ti == 1) ? Wkb : (ti == 2) ? Wvb : Wob;
    base = ((blk - 6144) & 511) * 2048;
  }
  int i = base + threadIdx.x * 8;
  float4 a = *(const float4*)(in + i);
  float4 b = *(const float4*)(in + i + 4);
  u16x8 o;
  o[0]=f2bf(a.x); o[1]=f2bf(a.y); o[2]=f2bf(a.z); o[3]=f2bf(a.w);
  o[4]=f2bf(b.x); o[5]=f2bf(b.y); o[6]=f2bf(b.z); o[7]=f2bf(b.w);
  *(u16x8*)(out + i) = o;
}

// ---- GEMM: Y[m][n] = sum_k X[m][k]*W[n][k] + bias[n] ----
// (MT*32)x128 tile (MT=4: 128x128; MT=2: 64x128), BK=64, 256 threads.
// Hoisted LDS offsets + incremental staging pointers. LDS declared in caller
// (R9 bug: per-instantiation static __shared__ -> 96KB).
// MODE 0/1/3: operand-swapped MFMA (reg axis along Y cols -> vector stores).
// MODE 2: V -> permuted VT scatter.
// R11 lesson: per-element atomic accumulate epilogues are banned (8x writes).
// R12 lesson: no forced launch_bounds (VGPR=64 -> 157MB scratch spills).
template <int MODE, int MT>
__device__ __forceinline__ void gemm_body(unsigned short* __restrict__ lA,
                                          unsigned short* __restrict__ lB,
                                          const unsigned short* __restrict__ X,
                                          const unsigned short* __restrict__ W,
                                          const float* __restrict__ bias,
                                          unsigned short* __restrict__ Yb,
                                          float* __restrict__ Yf,
                                          int rowBase, int colBase) {
  const int t = threadIdx.x;
  const int lane = t & 63, wave = t >> 6;
  const int cl = lane & 15, qd = lane >> 4;
  const int wm = wave >> 1, wn = wave & 1;
  const int srow = t >> 3, sslot = t & 7;

  // hoisted LDS read offsets (ushort indices), invariant across the k-loop
  int aoff[2][MT], boff[2][4];
  #pragma unroll
  for (int ks = 0; ks < 2; ks++) {
    #pragma unroll
    for (int i = 0; i < MT; i++) {
      int ra = wm * (MT * 16) + i * 16 + cl;
      aoff[ks][i] = ra * 64 + ((ks * 4 + qd) ^ (ra & 7)) * 8;
    }
    #pragma unroll
    for (int i = 0; i < 4; i++) {
      int rb = wn * 64 + i * 16 + cl;
      boff[ks][i] = rb * 64 + ((ks * 4 + qd) ^ (rb & 7)) * 8;
    }
  }
  // incremental staging pointers (advance 64 elems per k-step)
  const unsigned short* xp[MT];
  const unsigned short* wp[4];
  #pragma unroll
  for (int i = 0; i < MT; i++) {
    int r = i * 32 + srow;
    int chunk = sslot ^ (r & 7);
    xp[i] = X + (size_t)(rowBase + r) * DMODEL + chunk * 8;
  }
  #pragma unroll
  for (int i = 0; i < 4; i++) {
    int r = i * 32 + srow;
    int chunk = sslot ^ (r & 7);
    wp[i] = W + (size_t)(colBase + r) * DMODEL + chunk * 8;
  }

  f32x4 zero = {0.f, 0.f, 0.f, 0.f};
  f32x4 acc[MT][4];
  for (int mt = 0; mt < MT; mt++) for (int nt = 0; nt < 4; nt++) acc[mt][nt] = zero;

  for (int k0 = 0; k0 < DMODEL; k0 += 64) {
    __syncthreads();
    #pragma unroll
    for (int i = 0; i < MT; i++) {
      gld16(xp[i], (char*)lA + i * 4096 + wave * 1024);
      xp[i] += 64;
    }
    #pragma unroll
    for (int i = 0; i < 4; i++) {
      gld16(wp[i], (char*)lB + i * 4096 + wave * 1024);
      wp[i] += 64;
    }
    __syncthreads();
    #pragma unroll
    for (int ks = 0; ks < 2; ks++) {
      bf16x8 af[MT], bfr[4];
      #pragma unroll
      for (int mt = 0; mt < MT; mt++) af[mt] = *(const bf16x8*)&lA[aoff[ks][mt]];
      #pragma unroll
      for (int nt = 0; nt < 4; nt++) bfr[nt] = *(const bf16x8*)&lB[boff[ks][nt]];
      #pragma unroll
      for (int mt = 0; mt < MT; mt++)
        #pragma unroll
        for (int nt = 0; nt < 4; nt++) {
          if (MODE == 2)
            acc[mt][nt] = __builtin_amdgcn_mfma_f32_16x16x32_bf16(af[mt], bfr[nt], acc[mt][nt], 0, 0, 0);
          else  // swapped: D[m=Ycol][n=Yrow]
            acc[mt][nt] = __builtin_amdgcn_mfma_f32_16x16x32_bf16(bfr[nt], af[mt], acc[mt][nt], 0, 0, 0);
        }
    }
  }

  if (MODE == 2) {
    // original C/D layout: col(Ycol)=cl, row(Yrow)=qd*4+r
    // V projection -> permuted VT[(b*16+h)*64+d][s], s-nibbles reordered per
    // 32-half: l4<4 -> pos 2*l4 ; l4>=4 -> pos 2*(l4-4)+1
    #pragma unroll
    for (int mt = 0; mt < MT; mt++) {
      int row0 = rowBase + wm * (MT * 16) + mt * 16 + qd * 4;
      int bb = row0 >> 11;
      int s_in = row0 & 2047;
      int blk = s_in & ~63;
      int n4 = (s_in & 63) >> 2;
      int l4 = n4 & 7;
      int pos = 8 * (n4 >> 3) + ((l4 < 4) ? 2 * l4 : 2 * (l4 - 4) + 1);
      #pragma unroll
      for (int nt = 0; nt < 4; nt++) {
        int c = colBase + wn * 64 + nt * 16 + cl;
        float bv = bias[c];
        int hh = c >> 6, d = c & 63;
        u16x4 v;
        #pragma unroll
        for (int r = 0; r < 4; r++) v[r] = f2bf(acc[mt][nt][r] + bv);
        *(u16x4*)&Yb[(size_t)((bb * NHEAD + hh) * 64 + d) * SEQ + blk + pos * 4] = v;
      }
    }
  } else {
    // swapped C/D layout: n(Yrow)=cl, m(Ycol)=qd*4+r -> vector stores along cols
    #pragma unroll
    for (int nt = 0; nt < 4; nt++) {
      int col = colBase + wn * 64 + nt * 16 + qd * 4;
      f32x4 bv4 = *(const f32x4*)&bias[col];
      #pragma unroll
      for (int mt = 0; mt < MT; mt++) {
        int row = rowBase + wm * (MT * 16) + mt * 16 + cl;
        if (MODE == 3) {
          f32x4 v;
          #pragma unroll
          for (int r = 0; r < 4; r++) v[r] = acc[mt][nt][r] + bv4[r];
          *(f32x4*)&Yf[(size_t)row * DMODEL + col] = v;
        } else {
          u16x4 v;
          #pragma unroll
          for (int r = 0; r < 4; r++) {
            float x = acc[mt][nt][r] + bv4[r];
            v[r] = f2bf(MODE == 1 ? x * QSCALE : x);
          }
          *(u16x4*)&Yb[(size_t)row * DMODEL + col] = v;
        }
      }
    }
  }
}

// grid dim3(512,1,3): MT=2 (64x128 tiles) -> 1536 blocks = 6 blocks/CU
// (R13's gemm_out MT=2 win applied to qkv; was 3 blocks/CU at MT=4).
// y-fastest linearization (by = id&63): the 8 bx-blocks sharing an X panel
// have ids congruent mod 8 => same XCD.
__global__ __launch_bounds__(256)
void gemm_qkv(const unsigned short* __restrict__ Xq, const unsigned short* __restrict__ Xk,
              const unsigned short* __restrict__ Xv,
              const unsigned short* __restrict__ Wq, const unsigned short* __restrict__ Wk,
              const unsigned short* __restrict__ Wv,
              const float* __restrict__ bq, const float* __restrict__ bk,
              const float* __restrict__ bv,
              unsigned short* __restrict__ Q, unsigned short* __restrict__ K,
              unsigned short* __restrict__ VT) {
  __shared__ unsigned short lA[64 * 64];    // 8 KB (MT=2) — shared by all MODE paths
  __shared__ unsigned short lB[128 * 64];   // 16 KB
  int id = blockIdx.x;
  int by = id & 63, bx = id >> 6;
  int z = blockIdx.z;
  if (z == 0)      gemm_body<1, 2>(lA, lB, Xq, Wq, bq, Q,  nullptr, by * 64, bx * 128);
  else if (z == 1) gemm_body<0, 2>(lA, lB, Xk, Wk, bk, K,  nullptr, by * 64, bx * 128);
  else             gemm_body<2, 2>(lA, lB, Xv, Wv, bv, VT, nullptr, by * 64, bx * 128);
}

// grid 512: 64x128 tiles (MT=2) -> 2 blocks/CU. Plain stores, no atomics.
// Panel-sharers (same by, ids differing by 64) are congruent mod 8 => same XCD.
__global__ __launch_bounds__(256)
void gemm_out(const unsigned short* __restrict__ CTX, const unsigned short* __restrict__ Wo,
              const float* __restrict__ bo, float* __restrict__ out) {
  __shared__ unsigned short lA[64 * 64];    // 8 KB (MT=2)
  __shared__ unsigned short lB[128 * 64];   // 16 KB
  int id = blockIdx.x;
  int by = id & 63, bx = id >> 6;
  gemm_body<3, 2>(lA, lB, CTX, Wo, bo, nullptr, out, by * 64, bx * 128);
}

// ---- flash attention, transposed: S^T = K Q^T, O^T = V^T P^T ----
// R8 body. XCD swizzle: all 16 qt-blocks of one (h,b) land on one XCD so K/V
// tiles are fetched once per XCD (R10: FETCH 69.7 -> 12.3 MB).
__global__ __launch_bounds__(256)
void attn(const unsigned short* __restrict__ Q, const unsigned short* __restrict__ K,
          const unsigned short* __restrict__ VT, unsigned short* __restrict__ CTX) {
  __shared__ unsigned short lK[2 * 64 * 64];  // 16 KB (Q staged here first)
  __shared__ unsigned short lV[2 * 64 * 64];  // 16 KB, permuted VT tiles
  const int t = threadIdx.x, lane = t & 63, wave = t >> 6;
  const int cl = lane & 15, qd = lane >> 4;
  // XCD-aware remap: flat -> (xcd = flat&7, loc); (h,b) = p = xcd*4 + loc>>4
  const int flat = blockIdx.x + 16 * blockIdx.y + 256 * blockIdx.z;
  const int loc = flat >> 3;
  const int p = (flat & 7) * 4 + (loc >> 4);
  const int qt = loc & 15, h = p & 15, b = p >> 4;
  const int srow = t >> 3, sslot = t & 7;

  // stage 128 Q rows into lK halves
  #pragma unroll
  for (int half = 0; half < 2; half++)
    #pragma unroll
    for (int i = 0; i < 2; i++) {
      int r = i * 32 + srow;
      int chunk = sslot ^ (r & 7);
      gld16(Q + (size_t)(b * SEQ + qt * 128 + half * 64 + r) * DMODEL + h * 64 + chunk * 8,
            (char*)lK + half * 8192 + i * 4096 + wave * 1024);
    }
  __syncthreads();
  bf16x8 qf[2][2];
  #pragma unroll
  for (int qg = 0; qg < 2; qg++)
    #pragma unroll
    for (int ks = 0; ks < 2; ks++) {
      int r = wave * 16 + cl;
      int slot = (ks * 4 + qd) ^ (r & 7);
      qf[qg][ks] = *(const bf16x8*)&lK[qg * 4096 + r * 64 + slot * 8];
    }
  __syncthreads();  // all waves done reading Q before K staging overwrites

  // hoisted LDS read offsets (kt-invariant)
  int ka[8], va[8];
  #pragma unroll
  for (int ks = 0; ks < 2; ks++)
    #pragma unroll
    for (int nt = 0; nt < 4; nt++) {
      int rk = nt * 16 + cl;
      ka[ks * 4 + nt] = rk * 64 + ((ks * 4 + qd) ^ (rk & 7)) * 8;
    }
  #pragma unroll
  for (int ntp = 0; ntp < 2; ntp++)
    #pragma unroll
    for (int dt = 0; dt < 4; dt++) {
      int d = dt * 16 + cl;
      va[ntp * 4 + dt] = d * 64 + ((4 * ntp + qd) ^ (d & 7)) * 8;
    }

  // stage K/V tile 0 into buffer 0; init incremental prefetch pointers
  const unsigned short* kp[2];
  const unsigned short* vp[2];
  #pragma unroll
  for (int i = 0; i < 2; i++) {
    int r = i * 32 + srow;
    int chunk = sslot ^ (r & 7);
    kp[i] = K + (size_t)(b * SEQ + r) * DMODEL + h * 64 + chunk * 8;
    vp[i] = VT + (size_t)((b * NHEAD + h) * 64 + r) * SEQ + chunk * 8;
    gld16(kp[i], (char*)lK + i * 4096 + wave * 1024);
    gld16(vp[i], (char*)lV + i * 4096 + wave * 1024);
    kp[i] += 64 * DMODEL; vp[i] += 64;
  }

  f32x4 zero = {0.f, 0.f, 0.f, 0.f};
  f32x4 o[2][4];     // o[qg][dt][r] = O^T[d=dt*16+qd*4+r][q=cl]
  f32x4 osum[2];     // row-sum via ones-MFMA
  #pragma unroll
  for (int qg = 0; qg < 2; qg++) {
    #pragma unroll
    for (int dt = 0; dt < 4; dt++) o[qg][dt] = zero;
    osum[qg] = zero;
  }
  bf16x8 ones;
  #pragma unroll
  for (int j = 0; j < 8; j++) ones[j] = (__bf16)1.0f;

  #pragma unroll 2
  for (int kt = 0; kt < SEQ / 64; kt++) {
    const int cb = (kt & 1) * 4096;
    __syncthreads();  // tile kt's loads drained; other buffer free
    if (kt + 1 < SEQ / 64) {
      const int nb = ((kt + 1) & 1) * 8192;
      #pragma unroll
      for (int i = 0; i < 2; i++) {
        gld16(kp[i], (char*)lK + nb + i * 4096 + wave * 1024);
        gld16(vp[i], (char*)lV + nb + i * 4096 + wave * 1024);
        kp[i] += 64 * DMODEL; vp[i] += 64;
      }
    }

    // S^T[kv][q]: A = K rows, B = qf; kf shared across both q-groups
    f32x4 sc[2][4];
    #pragma unroll
    for (int qg = 0; qg < 2; qg++)
      #pragma unroll
      for (int nt = 0; nt < 4; nt++) sc[qg][nt] = zero;
    #pragma unroll
    for (int ks = 0; ks < 2; ks++)
      #pragma unroll
      for (int nt = 0; nt < 4; nt++) {
        bf16x8 kf = *(const bf16x8*)&lK[cb + ka[ks * 4 + nt]];
        sc[0][nt] = __builtin_amdgcn_mfma_f32_16x16x32_bf16(kf, qf[0][ks], sc[0][nt], 0, 0, 0);
        sc[1][nt] = __builtin_amdgcn_mfma_f32_16x16x32_bf16(kf, qf[1][ks], sc[1][nt], 0, 0, 0);
      }

    // P^T = 2^(S^T); pack straight to bf16 frags
    bf16x8 pb[2][2];
    #pragma unroll
    for (int qg = 0; qg < 2; qg++)
      #pragma unroll
      for (int ntp = 0; ntp < 2; ntp++) {
        bf16x8 x;
        #pragma unroll
        for (int j = 0; j < 4; j++)
          x[j] = (__bf16)__builtin_amdgcn_exp2f(sc[qg][2 * ntp][j]);
        #pragma unroll
        for (int j = 0; j < 4; j++)
          x[4 + j] = (__bf16)__builtin_amdgcn_exp2f(sc[qg][2 * ntp + 1][j]);
        pb[qg][ntp] = x;
      }

    // row-sum on the matrix pipe
    #pragma unroll
    for (int qg = 0; qg < 2; qg++) {
      osum[qg] = __builtin_amdgcn_mfma_f32_16x16x32_bf16(ones, pb[qg][0], osum[qg], 0, 0, 0);
      osum[qg] = __builtin_amdgcn_mfma_f32_16x16x32_bf16(ones, pb[qg][1], osum[qg], 0, 0, 0);
    }

    // O^T += V^T P^T; vf shared across both q-groups
    #pragma unroll
    for (int ntp = 0; ntp < 2; ntp++)
      #pragma unroll
      for (int dt = 0; dt < 4; dt++) {
        bf16x8 vf = *(const bf16x8*)&lV[cb + va[ntp * 4 + dt]];
        o[0][dt] = __builtin_amdgcn_mfma_f32_16x16x32_bf16(vf, pb[0][ntp], o[0][dt], 0, 0, 0);
        o[1][dt] = __builtin_amdgcn_mfma_f32_16x16x32_bf16(vf, pb[1][ntp], o[1][dt], 0, 0, 0);
      }
  }

  // epilogue: every lane holds its q-column's sum in osum[qg][0]
  #pragma unroll
  for (int qg = 0; qg < 2; qg++) {
    float inv = 1.f / osum[qg][0];
    int row = b * SEQ + qt * 128 + qg * 64 + wave * 16 + cl;
    #pragma unroll
    for (int dt = 0; dt < 4; dt++) {
      u16x4 v;
      #pragma unroll
      for (int r = 0; r < 4; r++) v[r] = f2bf(o[qg][dt][r] * inv);
      *(u16x4*)&CTX[(size_t)row * DMODEL + h * 64 + dt * 16 + qd * 4] = v;
    }
  }
}

extern "C" void kernel_launch(void* const* d_in, const int* in_sizes, int n_in,
                              void* d_out, int out_size, void* d_ws, size_t ws_size,
                              hipStream_t stream) {
  const float* q  = (const float*)d_in[0];
  const float* k  = (const float*)d_in[1];
  const float* v  = (const float*)d_in[2];
  const float* Wq = (const float*)d_in[3]; const float* bq = (const float*)d_in[4];
  const float* Wk = (const float*)d_in[5]; const float* bk = (const float*)d_in[6];
  const float* Wv = (const float*)d_in[7]; const float* bv = (const float*)d_in[8];
  const float* Wo = (const float*)d_in[9]; const float* bo = (const float*)d_in[10];
  float* out = (float*)d_out;

  char* ws = (char*)d_ws;
  const size_t MB = 1u << 20;
  // Liveness: Wob kept at +70MB (R4-R6 NaN was an Opart->Wob clobber)
  unsigned short* Xq  = (unsigned short*)(ws + 0 * MB);
  unsigned short* Xk  = (unsigned short*)(ws + 8 * MB);
  unsigned short* Xv  = (unsigned short*)(ws + 16 * MB);
  unsigned short* Wqb = (unsigned short*)(ws + 24 * MB);
  unsigned short* Wkb = (unsigned short*)(ws + 26 * MB);
  unsigned short* Wvb = (unsigned short*)(ws + 28 * MB);
  unsigned short* Wob = (unsigned short*)(ws + 70 * MB);
  unsigned short* Qp  = (unsigned short*)(ws + 32 * MB);
  unsigned short* Kp  = (unsigned short*)(ws + 40 * MB);
  unsigned short* VT  = (unsigned short*)(ws + 48 * MB);
  unsigned short* CTX = (unsigned short*)(ws + 56 * MB);

  cvt_all<<<8192, 256, 0, stream>>>(q, k, v, Wq, Wk, Wv, Wo,
                                    Xq, Xk, Xv, Wqb, Wkb, Wvb, Wob);

  gemm_qkv<<<dim3(512, 1, 3), 256, 0, stream>>>(
      Xq, Xk, Xv, Wqb, Wkb, Wvb, bq, bk, bv, Qp, Kp, VT);

  attn<<<dim3(SEQ / 128, NHEAD, BATCH), 256, 0, stream>>>(Qp, Kp, VT, CTX);

  gemm_out<<<512, 256, 0, stream>>>(CTX, Wob, bo, out);
}